// Round 1
// baseline (1363.976 us; speedup 1.0000x reference)
//
#include <hip/hip_runtime.h>

typedef __bf16 bf16;
typedef __bf16 bf16x8 __attribute__((ext_vector_type(8)));
typedef float f32x4 __attribute__((ext_vector_type(4)));

static_assert(sizeof(bf16x8) == 16, "bf16x8 must be 16B");

// ---------------- fp32 -> bf16 bulk convert ----------------
__global__ void cvt_f32_bf16(const float* __restrict__ src, bf16* __restrict__ dst, long n) {
  long i = ((long)blockIdx.x * 256 + threadIdx.x) * 8;
  long stride = (long)gridDim.x * 2048;
  for (; i < n; i += stride) {
    float4 a = *(const float4*)(src + i);
    float4 b = *(const float4*)(src + i + 4);
    bf16x8 o;
    o[0] = (bf16)a.x; o[1] = (bf16)a.y; o[2] = (bf16)a.z; o[3] = (bf16)a.w;
    o[4] = (bf16)b.x; o[5] = (bf16)b.y; o[6] = (bf16)b.z; o[7] = (bf16)b.w;
    *(bf16x8*)(dst + i) = o;
  }
}

// ---------------- generic NT GEMM: C[M,N] = A[M,K] * Bt[N,K]^T ----------------
// A may be a concat of two buffers along K (split at KA0). Batched via blockIdx.z.
// EPI: 0 = none, 1 = elu(x)+1, 2 = * rowscale[row], 3 = relu. Output bf16.
template<int EPI>
__launch_bounds__(256)
__global__ void gemm_bt(const bf16* __restrict__ A0, const bf16* __restrict__ A1, int KA0,
                        const bf16* __restrict__ Bt, bf16* __restrict__ C,
                        int M, int N, int K,
                        long sAb, long sBb, long sCb,
                        const float* __restrict__ rowscale)
{
  __shared__ bf16 sA[128 * 72];
  __shared__ bf16 sB[128 * 72];
  const int tid = threadIdx.x;
  const int lane = tid & 63, wave = tid >> 6;
  const int wm = (wave & 1) << 6, wn = (wave >> 1) << 6;
  const int lr = lane & 15, lq = lane >> 4;
  const long zb = blockIdx.z;
  const bf16* A0p = A0 + zb * sAb;
  const bf16* Btp = Bt + zb * sBb;
  bf16* Cp = C + zb * sCb;
  const int bm = blockIdx.x << 7, bn = blockIdx.y << 7;
  const int KA1 = K - KA0;

  f32x4 acc[4][4];
#pragma unroll
  for (int i = 0; i < 4; i++)
#pragma unroll
    for (int j = 0; j < 4; j++) acc[i][j] = (f32x4){0.f, 0.f, 0.f, 0.f};

  for (int k0 = 0; k0 < K; k0 += 64) {
#pragma unroll
    for (int i = 0; i < 4; i++) {
      int idx = tid + (i << 8);
      int r = idx >> 3, c = (idx & 7) << 3;
      int gk = k0 + c;
      bf16x8 v;
      if (gk < KA0) v = *(const bf16x8*)(A0p + (long)(bm + r) * KA0 + gk);
      else          v = *(const bf16x8*)(A1  + (long)(bm + r) * KA1 + (gk - KA0));
      *(bf16x8*)(&sA[r * 72 + c]) = v;
    }
#pragma unroll
    for (int i = 0; i < 4; i++) {
      int idx = tid + (i << 8);
      int r = idx >> 3, c = (idx & 7) << 3;
      bf16x8 v = *(const bf16x8*)(Btp + (long)(bn + r) * K + k0 + c);
      *(bf16x8*)(&sB[r * 72 + c]) = v;
    }
    __syncthreads();
#pragma unroll
    for (int kk = 0; kk < 64; kk += 32) {
      bf16x8 af[4], bfv[4];
#pragma unroll
      for (int t = 0; t < 4; t++) af[t]  = *(const bf16x8*)(&sA[(wm + (t << 4) + lr) * 72 + kk + (lq << 3)]);
#pragma unroll
      for (int t = 0; t < 4; t++) bfv[t] = *(const bf16x8*)(&sB[(wn + (t << 4) + lr) * 72 + kk + (lq << 3)]);
#pragma unroll
      for (int mt = 0; mt < 4; mt++)
#pragma unroll
        for (int nt = 0; nt < 4; nt++)
          acc[mt][nt] = __builtin_amdgcn_mfma_f32_16x16x32_bf16(af[mt], bfv[nt], acc[mt][nt], 0, 0, 0);
    }
    __syncthreads();
  }

  // C/D layout: col = lane&15, row = (lane>>4)*4 + reg (m89/m91 verified)
#pragma unroll
  for (int mt = 0; mt < 4; mt++) {
#pragma unroll
    for (int r = 0; r < 4; r++) {
      int row = bm + wm + (mt << 4) + (lq << 2) + r;
      float rs = 1.f;
      if constexpr (EPI == 2) rs = rowscale[zb * (long)M + row];
#pragma unroll
      for (int nt = 0; nt < 4; nt++) {
        int col = bn + wn + (nt << 4) + lr;
        float v = acc[mt][nt][r];
        if constexpr (EPI == 1) v = v > 0.f ? v + 1.f : __expf(v);
        if constexpr (EPI == 2) v = v * rs;
        if constexpr (EPI == 3) v = v > 0.f ? v : 0.f;
        Cp[(long)row * N + col] = (bf16)v;
      }
    }
  }
}

// ---------------- batched TN GEMM: C[n][v,d] = sum_s A[n][s,v] * B[n][s,d] ----------------
// A,B: [S x 512] per batch, C: [512 x 512] per batch. Transposed LDS staging.
__launch_bounds__(256)
__global__ void gemm_tn_b(const bf16* __restrict__ Ab, const bf16* __restrict__ Bb,
                          bf16* __restrict__ C, int S)
{
  __shared__ bf16 sA[128 * 72];
  __shared__ bf16 sB[128 * 72];
  const int tid = threadIdx.x;
  const int lane = tid & 63, wave = tid >> 6;
  const int wm = (wave & 1) << 6, wn = (wave >> 1) << 6;
  const int lr = lane & 15, lq = lane >> 4;
  const long zb = blockIdx.z;
  const bf16* A = Ab + zb * (long)S * 512;
  const bf16* B = Bb + zb * (long)S * 512;
  bf16* Cp = C + zb * (512L * 512L);
  const int bm = blockIdx.x << 7, bn = blockIdx.y << 7;

  f32x4 acc[4][4];
#pragma unroll
  for (int i = 0; i < 4; i++)
#pragma unroll
    for (int j = 0; j < 4; j++) acc[i][j] = (f32x4){0.f, 0.f, 0.f, 0.f};

  for (int s0 = 0; s0 < S; s0 += 64) {
#pragma unroll
    for (int i = 0; i < 4; i++) {
      int idx = tid + (i << 8);
      int sl = idx >> 4, c = (idx & 15) << 3;
      bf16x8 v = *(const bf16x8*)(A + (long)(s0 + sl) * 512 + bm + c);
#pragma unroll
      for (int j = 0; j < 8; j++) sA[(c + j) * 72 + sl] = v[j];
    }
#pragma unroll
    for (int i = 0; i < 4; i++) {
      int idx = tid + (i << 8);
      int sl = idx >> 4, c = (idx & 15) << 3;
      bf16x8 v = *(const bf16x8*)(B + (long)(s0 + sl) * 512 + bn + c);
#pragma unroll
      for (int j = 0; j < 8; j++) sB[(c + j) * 72 + sl] = v[j];
    }
    __syncthreads();
#pragma unroll
    for (int kk = 0; kk < 64; kk += 32) {
      bf16x8 af[4], bfv[4];
#pragma unroll
      for (int t = 0; t < 4; t++) af[t]  = *(const bf16x8*)(&sA[(wm + (t << 4) + lr) * 72 + kk + (lq << 3)]);
#pragma unroll
      for (int t = 0; t < 4; t++) bfv[t] = *(const bf16x8*)(&sB[(wn + (t << 4) + lr) * 72 + kk + (lq << 3)]);
#pragma unroll
      for (int mt = 0; mt < 4; mt++)
#pragma unroll
        for (int nt = 0; nt < 4; nt++)
          acc[mt][nt] = __builtin_amdgcn_mfma_f32_16x16x32_bf16(af[mt], bfv[nt], acc[mt][nt], 0, 0, 0);
    }
    __syncthreads();
  }

#pragma unroll
  for (int mt = 0; mt < 4; mt++) {
#pragma unroll
    for (int r = 0; r < 4; r++) {
      int row = bm + wm + (mt << 4) + (lq << 2) + r;
#pragma unroll
      for (int nt = 0; nt < 4; nt++) {
        int col = bn + wn + (nt << 4) + lr;
        Cp[(long)row * 512 + col] = (bf16)acc[mt][nt][r];
      }
    }
  }
}

// ---------------- Ksum[n,d] = sum_s K[n,s,d] ----------------
__global__ void ksum_kernel(const bf16* __restrict__ Kb, float* __restrict__ Ksum) {
  int d = blockIdx.x * 256 + threadIdx.x;
  long n = blockIdx.y;
  const bf16* p = Kb + n * (1024L * 512L) + d;
  float s = 0.f;
  for (int i = 0; i < 1024; i++) s += (float)p[(long)i * 512];
  Ksum[n * 512 + d] = s;
}

// ---------------- Z[row] = 1/(dot(Q[row], Ksum[n]) + eps), wave per row ----------------
__launch_bounds__(256)
__global__ void z_kernel(const bf16* __restrict__ Qb, const float* __restrict__ Ksum, float* __restrict__ Z) {
  const int wave = threadIdx.x >> 6, lane = threadIdx.x & 63;
  const long row = (long)blockIdx.x * 4 + wave;
  const long n = row >> 10;
  bf16x8 qv = *(const bf16x8*)(Qb + row * 512 + lane * 8);
  const float* ks = Ksum + n * 512 + lane * 8;
  float4 k0 = *(const float4*)ks;
  float4 k1 = *(const float4*)(ks + 4);
  float dot = (float)qv[0] * k0.x + (float)qv[1] * k0.y + (float)qv[2] * k0.z + (float)qv[3] * k0.w
            + (float)qv[4] * k1.x + (float)qv[5] * k1.y + (float)qv[6] * k1.z + (float)qv[7] * k1.w;
#pragma unroll
  for (int off = 32; off > 0; off >>= 1) dot += __shfl_xor(dot, off);
  if (lane == 0) Z[row] = 1.f / (dot + 1e-6f);
}

// ---------------- LayerNorm, wave per row of 512. MODE 0: bf16 out = LN*g+b.
// MODE 1: float out = xres + LN*g+b ----------------
template<int MODE>
__launch_bounds__(256)
__global__ void ln_kernel(const bf16* __restrict__ T, const float* __restrict__ g, const float* __restrict__ b,
                          const float* __restrict__ xres, void* __restrict__ outp)
{
  const int wave = threadIdx.x >> 6, lane = threadIdx.x & 63;
  const long row = (long)blockIdx.x * 4 + wave;
  const int c = lane * 8;
  bf16x8 tv = *(const bf16x8*)(T + row * 512 + c);
  float v[8]; float s = 0.f;
#pragma unroll
  for (int j = 0; j < 8; j++) { v[j] = (float)tv[j]; s += v[j]; }
#pragma unroll
  for (int off = 32; off > 0; off >>= 1) s += __shfl_xor(s, off);
  const float mu = s * (1.f / 512.f);
  float q = 0.f;
#pragma unroll
  for (int j = 0; j < 8; j++) { float d = v[j] - mu; q += d * d; }
#pragma unroll
  for (int off = 32; off > 0; off >>= 1) q += __shfl_xor(q, off);
  const float rstd = rsqrtf(q * (1.f / 512.f) + 1e-5f);
  float h[8];
#pragma unroll
  for (int j = 0; j < 8; j++) h[j] = (v[j] - mu) * rstd * g[c + j] + b[c + j];
  if constexpr (MODE == 0) {
    bf16x8 o;
#pragma unroll
    for (int j = 0; j < 8; j++) o[j] = (bf16)h[j];
    *(bf16x8*)((bf16*)outp + row * 512 + c) = o;
  } else {
    const float* xr = xres + row * 512 + c;
    float4 x0 = *(const float4*)xr, x1 = *(const float4*)(xr + 4);
    float4 o0 = {x0.x + h[0], x0.y + h[1], x0.z + h[2], x0.w + h[3]};
    float4 o1 = {x1.x + h[4], x1.y + h[5], x1.z + h[6], x1.w + h[7]};
    float* op = (float*)outp + row * 512 + c;
    *(float4*)op = o0;
    *(float4*)(op + 4) = o1;
  }
}

// ---------------- launch ----------------
extern "C" void kernel_launch(void* const* d_in, const int* in_sizes, int n_in,
                              void* d_out, int out_size, void* d_ws, size_t ws_size,
                              hipStream_t stream) {
  const float* x      = (const float*)d_in[0];
  const float* source = (const float*)d_in[1];
  const float* Wq = (const float*)d_in[2];
  const float* Wk = (const float*)d_in[3];
  const float* Wv = (const float*)d_in[4];
  const float* Wm = (const float*)d_in[5];
  const float* W1 = (const float*)d_in[6];
  const float* W2 = (const float*)d_in[7];
  const float* g1 = (const float*)d_in[8];
  const float* b1 = (const float*)d_in[9];
  const float* g2 = (const float*)d_in[10];
  const float* b2 = (const float*)d_in[11];
  float* out = (float*)d_out;

  char* ws = (char*)d_ws;
  // workspace layout (bytes)
  bf16* xb   = (bf16*)(ws + 0L);           // 64 MB, lives to G6
  bf16* sb   = (bf16*)(ws + 67108864L);    // 64 MB -> reused as msgn after G3
  bf16* Qb   = (bf16*)(ws + 134217728L);   // 64 MB -> reused (with Kb slot) as h1
  bf16* Kb   = (bf16*)(ws + 201326592L);   // 64 MB -> reused as msg_pre
  bf16* Vb   = (bf16*)(ws + 268435456L);   // 64 MB -> reused as t1, then t2
  bf16* KVt  = (bf16*)(ws + 335544320L);   // 32 MB
  float* Ksum = (float*)(ws + 369098752L); // 128 KB
  float* Zbuf = (float*)(ws + 369229824L); // 256 KB
  bf16* Wqb = (bf16*)(ws + 369491968L);    // 512 KB
  bf16* Wkb = (bf16*)(ws + 370016256L);
  bf16* Wvb = (bf16*)(ws + 370540544L);
  bf16* Wmb = (bf16*)(ws + 371064832L);
  bf16* W1b = (bf16*)(ws + 371589120L);    // 2 MB
  bf16* W2b = (bf16*)(ws + 373686272L);    // 1 MB
  // aliases
  bf16* msg  = Kb;
  bf16* t1   = Vb;
  bf16* msgn = sb;
  bf16* h1   = Qb;   // 128 MB spanning Qb+Kb slots
  bf16* t2   = Vb;

  // 1. convert all fp32 inputs to bf16
  cvt_f32_bf16<<<16384, 256, 0, stream>>>(x, xb, 33554432L);
  cvt_f32_bf16<<<16384, 256, 0, stream>>>(source, sb, 33554432L);
  cvt_f32_bf16<<<128, 256, 0, stream>>>(Wq, Wqb, 262144L);
  cvt_f32_bf16<<<128, 256, 0, stream>>>(Wk, Wkb, 262144L);
  cvt_f32_bf16<<<128, 256, 0, stream>>>(Wv, Wvb, 262144L);
  cvt_f32_bf16<<<128, 256, 0, stream>>>(Wm, Wmb, 262144L);
  cvt_f32_bf16<<<512, 256, 0, stream>>>(W1, W1b, 1048576L);
  cvt_f32_bf16<<<256, 256, 0, stream>>>(W2, W2b, 524288L);

  // 2-4. projections (Q,K get elu+1 epilogue; note v/1024 and *1024 cancel exactly)
  gemm_bt<1><<<dim3(512, 4, 1), 256, 0, stream>>>(xb, nullptr, 512, Wqb, Qb, 65536, 512, 512, 0, 0, 0, nullptr);
  gemm_bt<1><<<dim3(512, 4, 1), 256, 0, stream>>>(sb, nullptr, 512, Wkb, Kb, 65536, 512, 512, 0, 0, 0, nullptr);
  gemm_bt<0><<<dim3(512, 4, 1), 256, 0, stream>>>(sb, nullptr, 512, Wvb, Vb, 65536, 512, 512, 0, 0, 0, nullptr);

  // 5. Ksum
  ksum_kernel<<<dim3(2, 64), 256, 0, stream>>>(Kb, Ksum);

  // 6. KVt[n][v,d] = sum_s V[n,s,v] * K[n,s,d]
  gemm_tn_b<<<dim3(4, 4, 64), 256, 0, stream>>>(Vb, Kb, KVt, 1024);

  // 7. Z
  z_kernel<<<16384, 256, 0, stream>>>(Qb, Ksum, Zbuf);

  // 8. msg_pre[n,l,v] = (Q[n,l,:] . KVt[n][v,:]) * Z[n,l]   (batched)
  gemm_bt<2><<<dim3(8, 4, 64), 256, 0, stream>>>(Qb, nullptr, 512, KVt, msg, 1024, 512, 512,
                                                 1024L * 512, 512L * 512, 1024L * 512, Zbuf);

  // 9. t1 = msg_pre @ Wm^T
  gemm_bt<0><<<dim3(512, 4, 1), 256, 0, stream>>>(msg, nullptr, 512, Wmb, t1, 65536, 512, 512, 0, 0, 0, nullptr);

  // 10. msgn = LN(t1)*g1+b1
  ln_kernel<0><<<16384, 256, 0, stream>>>(t1, g1, b1, nullptr, msgn);

  // 11. h1 = relu([xb | msgn] @ W1^T)  (K=1024 concat)
  gemm_bt<3><<<dim3(512, 8, 1), 256, 0, stream>>>(xb, msgn, 512, W1b, h1, 65536, 1024, 1024, 0, 0, 0, nullptr);

  // 12. t2 = h1 @ W2^T
  gemm_bt<0><<<dim3(512, 4, 1), 256, 0, stream>>>(h1, nullptr, 1024, W2b, t2, 65536, 512, 1024, 0, 0, 0, nullptr);

  // 13. out = x + LN(t2)*g2+b2
  ln_kernel<1><<<16384, 256, 0, stream>>>(t2, g2, b2, x, out);

  (void)in_sizes; (void)n_in; (void)out_size; (void)ws_size;
}

// Round 2
// 1079.543 us; speedup vs baseline: 1.2635x; 1.2635x over previous
//
#include <hip/hip_runtime.h>

typedef __bf16 bf16;
typedef __bf16 bf16x4 __attribute__((ext_vector_type(4)));
typedef __bf16 bf16x8 __attribute__((ext_vector_type(8)));
typedef float f32x4 __attribute__((ext_vector_type(4)));

static_assert(sizeof(bf16x8) == 16, "bf16x8 must be 16B");

// async global->LDS, 16B per lane, lane-contiguous LDS destination
#define GLL16(gp, lp) __builtin_amdgcn_global_load_lds( \
    (__attribute__((address_space(1))) void*)(gp),      \
    (__attribute__((address_space(3))) void*)(lp), 16, 0, 0)

// ---------------- fp32 -> bf16 bulk convert ----------------
__global__ void cvt_f32_bf16(const float* __restrict__ src, bf16* __restrict__ dst, long n) {
  long i = ((long)blockIdx.x * 256 + threadIdx.x) * 8;
  long stride = (long)gridDim.x * 2048;
  for (; i < n; i += stride) {
    float4 a = *(const float4*)(src + i);
    float4 b = *(const float4*)(src + i + 4);
    bf16x8 o;
    o[0] = (bf16)a.x; o[1] = (bf16)a.y; o[2] = (bf16)a.z; o[3] = (bf16)a.w;
    o[4] = (bf16)b.x; o[5] = (bf16)b.y; o[6] = (bf16)b.z; o[7] = (bf16)b.w;
    *(bf16x8*)(dst + i) = o;
  }
}

// ---------------- generic NT GEMM: C[M,N] = A[M,K] * Bt[N,K]^T ----------------
// A may be a concat of two buffers along K (split at KA0, 64-aligned). Batched via blockIdx.z.
// EPI: 0 = none, 1 = elu(x)+1, 2 = * rowscale[row], 3 = relu.
// EPO: 0 = row-major bf16 C[M,N]; 1 = per-batch transposed Ct[n][col, l] with
//      L=1024 rows/batch, out row-stride 1024, batch stride 512*1024 (projection use only).
// LDS: [128][64] tiles, col-block XOR-swizzled by (row&7) so the global_load_lds
//      lane-contiguous write AND the ds_read_b128 fragment reads are both conflict-free.
template<int EPI, int EPO>
__launch_bounds__(256)
__global__ void gemm_bt(const bf16* __restrict__ A0, const bf16* __restrict__ A1, int KA0,
                        const bf16* __restrict__ Bt, bf16* __restrict__ C,
                        int M, int N, int K,
                        long sAb, long sBb, long sCb,
                        const float* __restrict__ rowscale)
{
  constexpr int SMEM_BYTES = (EPO == 1) ? (128 * 132 * 2) : (2 * 128 * 64 * 2);
  __shared__ __align__(16) char smem[SMEM_BYTES];
  bf16* sA = (bf16*)smem;          // [128][64], swizzled
  bf16* sB = sA + 128 * 64;

  const int tid = threadIdx.x;
  const int lane = tid & 63, wave = tid >> 6;
  const int wm = (wave & 1) << 6, wn = (wave >> 1) << 6;
  const int lr = lane & 15, lq = lane >> 4;
  const long zb = blockIdx.z;
  const bf16* A0p = A0 + zb * sAb;
  const bf16* Btp = Bt + zb * sBb;
  bf16* Cp = C + zb * sCb;
  const int bm = blockIdx.x << 7, bn = blockIdx.y << 7;

  // staging geometry: wave w loads rows [w*32, w*32+32) of each tile, 4 insts x 8 rows
  const int srow = wave << 5;
  const int lrow = lane >> 3;                 // 0..7 within 8-row slab
  const int lcb  = (lane & 7) ^ lrow;         // swizzled col-block this lane fetches

  f32x4 acc[4][4];
#pragma unroll
  for (int i = 0; i < 4; i++)
#pragma unroll
    for (int j = 0; j < 4; j++) acc[i][j] = (f32x4){0.f, 0.f, 0.f, 0.f};

  for (int k0 = 0; k0 < K; k0 += 64) {
    const bf16* Ap; int ka; long strA;
    if (k0 < KA0) { Ap = A0p; ka = k0;       strA = KA0;     }
    else          { Ap = A1;  ka = k0 - KA0; strA = K - KA0; }
#pragma unroll
    for (int i = 0; i < 4; i++) {
      int r = srow + (i << 3);
      GLL16(Ap  + (long)(bm + r + lrow) * strA + ka + (lcb << 3), sA + (r << 6));
      GLL16(Btp + (long)(bn + r + lrow) * K    + k0 + (lcb << 3), sB + (r << 6));
    }
    __syncthreads();
#pragma unroll
    for (int kk = 0; kk < 64; kk += 32) {
      const int kbx = ((kk >> 3) + lq) ^ (lr & 7);  // swizzled block for this lane
      bf16x8 af[4], bfv[4];
#pragma unroll
      for (int t = 0; t < 4; t++) {
        af[t]  = *(const bf16x8*)(&sA[((wm + (t << 4) + lr) << 6) + (kbx << 3)]);
        bfv[t] = *(const bf16x8*)(&sB[((wn + (t << 4) + lr) << 6) + (kbx << 3)]);
      }
#pragma unroll
      for (int mt = 0; mt < 4; mt++)
#pragma unroll
        for (int nt = 0; nt < 4; nt++)
          acc[mt][nt] = __builtin_amdgcn_mfma_f32_16x16x32_bf16(af[mt], bfv[nt], acc[mt][nt], 0, 0, 0);
    }
    __syncthreads();
  }

  if constexpr (EPO == 0) {
    // C/D layout: col = lane&15, row = (lane>>4)*4 + reg
#pragma unroll
    for (int mt = 0; mt < 4; mt++) {
#pragma unroll
      for (int r = 0; r < 4; r++) {
        int row = bm + wm + (mt << 4) + (lq << 2) + r;
        float rs = 1.f;
        if constexpr (EPI == 2) rs = rowscale[zb * (long)M + row];
#pragma unroll
        for (int nt = 0; nt < 4; nt++) {
          int col = bn + wn + (nt << 4) + lr;
          float v = acc[mt][nt][r];
          if constexpr (EPI == 1) v = v > 0.f ? v + 1.f : __expf(v);
          if constexpr (EPI == 2) v = v * rs;
          if constexpr (EPI == 3) v = v > 0.f ? v : 0.f;
          Cp[(long)row * N + col] = (bf16)v;
        }
      }
    }
  } else {
    // transpose the 128x128 tile through LDS, then coalesced transposed store.
    bf16* sT = (bf16*)smem;   // [128 cols][132]  (stride 132 elem = 66 words -> bank spread)
#pragma unroll
    for (int nt = 0; nt < 4; nt++) {
      int tc = wn + (nt << 4) + lr;
#pragma unroll
      for (int mt = 0; mt < 4; mt++) {
        bf16x4 p;
#pragma unroll
        for (int r = 0; r < 4; r++) {
          float v = acc[mt][nt][r];
          if constexpr (EPI == 1) v = v > 0.f ? v + 1.f : __expf(v);
          p[r] = (bf16)v;
        }
        *(bf16x4*)(&sT[tc * 132 + wm + (mt << 4) + (lq << 2)]) = p;
      }
    }
    __syncthreads();
    const long nidx = bm >> 10;          // batch (L=1024 rows per batch, bm 128-aligned)
    const int lbase = bm & 1023;
    const int c8 = tid >> 3, part = tid & 7;
#pragma unroll
    for (int cg = 0; cg < 4; cg++) {
      int col = (cg << 5) + c8;
#pragma unroll
      for (int j = 0; j < 2; j++) {
        int ro = (j << 6) + (part << 3);
        bf16x8 v = *(const bf16x8*)(&sT[col * 132 + ro]);
        *(bf16x8*)(&C[nidx * (512L * 1024L) + (long)(bn + col) * 1024L + lbase + ro]) = v;
      }
    }
  }
}

// ---------------- Ksum[n,d] = sum_s Kt[n][d,s] (contiguous rows) ----------------
__launch_bounds__(256)
__global__ void ksum_t(const bf16* __restrict__ Kt, float* __restrict__ Ksum) {
  const int wave = threadIdx.x >> 6, lane = threadIdx.x & 63;
  const long row = (long)blockIdx.x * 4 + wave;       // row = n*512 + d, 32768 rows
  const bf16* p = Kt + row * 1024 + lane * 16;
  bf16x8 a = *(const bf16x8*)p;
  bf16x8 b = *(const bf16x8*)(p + 8);
  float s = 0.f;
#pragma unroll
  for (int j = 0; j < 8; j++) s += (float)a[j] + (float)b[j];
#pragma unroll
  for (int off = 32; off > 0; off >>= 1) s += __shfl_xor(s, off);
  if (lane == 0) Ksum[row] = s;
}

// ---------------- Z[row] = 1/(dot(Q[row], Ksum[n]) + eps), wave per row ----------------
__launch_bounds__(256)
__global__ void z_kernel(const bf16* __restrict__ Qb, const float* __restrict__ Ksum, float* __restrict__ Z) {
  const int wave = threadIdx.x >> 6, lane = threadIdx.x & 63;
  const long row = (long)blockIdx.x * 4 + wave;
  const long n = row >> 10;
  bf16x8 qv = *(const bf16x8*)(Qb + row * 512 + lane * 8);
  const float* ks = Ksum + n * 512 + lane * 8;
  float4 k0 = *(const float4*)ks;
  float4 k1 = *(const float4*)(ks + 4);
  float dot = (float)qv[0] * k0.x + (float)qv[1] * k0.y + (float)qv[2] * k0.z + (float)qv[3] * k0.w
            + (float)qv[4] * k1.x + (float)qv[5] * k1.y + (float)qv[6] * k1.z + (float)qv[7] * k1.w;
#pragma unroll
  for (int off = 32; off > 0; off >>= 1) dot += __shfl_xor(dot, off);
  if (lane == 0) Z[row] = 1.f / (dot + 1e-6f);
}

// ---------------- LayerNorm, wave per row of 512. MODE 0: bf16 out = LN*g+b.
// MODE 1: float out = xres + LN*g+b ----------------
template<int MODE>
__launch_bounds__(256)
__global__ void ln_kernel(const bf16* __restrict__ T, const float* __restrict__ g, const float* __restrict__ b,
                          const float* __restrict__ xres, void* __restrict__ outp)
{
  const int wave = threadIdx.x >> 6, lane = threadIdx.x & 63;
  const long row = (long)blockIdx.x * 4 + wave;
  const int c = lane * 8;
  bf16x8 tv = *(const bf16x8*)(T + row * 512 + c);
  float v[8]; float s = 0.f;
#pragma unroll
  for (int j = 0; j < 8; j++) { v[j] = (float)tv[j]; s += v[j]; }
#pragma unroll
  for (int off = 32; off > 0; off >>= 1) s += __shfl_xor(s, off);
  const float mu = s * (1.f / 512.f);
  float q = 0.f;
#pragma unroll
  for (int j = 0; j < 8; j++) { float d = v[j] - mu; q += d * d; }
#pragma unroll
  for (int off = 32; off > 0; off >>= 1) q += __shfl_xor(q, off);
  const float rstd = rsqrtf(q * (1.f / 512.f) + 1e-5f);
  float h[8];
#pragma unroll
  for (int j = 0; j < 8; j++) h[j] = (v[j] - mu) * rstd * g[c + j] + b[c + j];
  if constexpr (MODE == 0) {
    bf16x8 o;
#pragma unroll
    for (int j = 0; j < 8; j++) o[j] = (bf16)h[j];
    *(bf16x8*)((bf16*)outp + row * 512 + c) = o;
  } else {
    const float* xr = xres + row * 512 + c;
    float4 x0 = *(const float4*)xr, x1 = *(const float4*)(xr + 4);
    float4 o0 = {x0.x + h[0], x0.y + h[1], x0.z + h[2], x0.w + h[3]};
    float4 o1 = {x1.x + h[4], x1.y + h[5], x1.z + h[6], x1.w + h[7]};
    float* op = (float*)outp + row * 512 + c;
    *(float4*)op = o0;
    *(float4*)(op + 4) = o1;
  }
}

// ---------------- launch ----------------
extern "C" void kernel_launch(void* const* d_in, const int* in_sizes, int n_in,
                              void* d_out, int out_size, void* d_ws, size_t ws_size,
                              hipStream_t stream) {
  const float* x      = (const float*)d_in[0];
  const float* source = (const float*)d_in[1];
  const float* Wq = (const float*)d_in[2];
  const float* Wk = (const float*)d_in[3];
  const float* Wv = (const float*)d_in[4];
  const float* Wm = (const float*)d_in[5];
  const float* W1 = (const float*)d_in[6];
  const float* W2 = (const float*)d_in[7];
  const float* g1 = (const float*)d_in[8];
  const float* b1 = (const float*)d_in[9];
  const float* g2 = (const float*)d_in[10];
  const float* b2 = (const float*)d_in[11];
  float* out = (float*)d_out;

  char* ws = (char*)d_ws;
  bf16* xb   = (bf16*)(ws + 0L);           // 64 MB
  bf16* sb   = (bf16*)(ws + 67108864L);    // 64 MB -> reused as msgn
  bf16* Qb   = (bf16*)(ws + 134217728L);   // 64 MB -> reused (with Kt slot) as h1
  bf16* Kt   = (bf16*)(ws + 201326592L);   // 64 MB [n][d][s] -> reused as msg
  bf16* Vt   = (bf16*)(ws + 268435456L);   // 64 MB [n][v][s] -> reused as t1/t2
  bf16* KVt  = (bf16*)(ws + 335544320L);   // 32 MB [n][v][d]
  float* Ksum = (float*)(ws + 369098752L); // 128 KB
  float* Zbuf = (float*)(ws + 369229824L); // 256 KB
  bf16* Wqb = (bf16*)(ws + 369491968L);
  bf16* Wkb = (bf16*)(ws + 370016256L);
  bf16* Wvb = (bf16*)(ws + 370540544L);
  bf16* Wmb = (bf16*)(ws + 371064832L);
  bf16* W1b = (bf16*)(ws + 371589120L);
  bf16* W2b = (bf16*)(ws + 373686272L);
  bf16* msg  = Kt;
  bf16* t1   = Vt;
  bf16* msgn = sb;
  bf16* h1   = Qb;
  bf16* t2   = Vt;

  // 1. fp32 -> bf16
  cvt_f32_bf16<<<16384, 256, 0, stream>>>(x, xb, 33554432L);
  cvt_f32_bf16<<<16384, 256, 0, stream>>>(source, sb, 33554432L);
  cvt_f32_bf16<<<128, 256, 0, stream>>>(Wq, Wqb, 262144L);
  cvt_f32_bf16<<<128, 256, 0, stream>>>(Wk, Wkb, 262144L);
  cvt_f32_bf16<<<128, 256, 0, stream>>>(Wv, Wvb, 262144L);
  cvt_f32_bf16<<<128, 256, 0, stream>>>(Wm, Wmb, 262144L);
  cvt_f32_bf16<<<512, 256, 0, stream>>>(W1, W1b, 1048576L);
  cvt_f32_bf16<<<256, 256, 0, stream>>>(W2, W2b, 524288L);

  // 2-4. projections. Q normal layout; K,V transposed per batch (EPO=1).
  gemm_bt<1,0><<<dim3(512, 4, 1), 256, 0, stream>>>(xb, nullptr, 512, Wqb, Qb, 65536, 512, 512, 0, 0, 0, nullptr);
  gemm_bt<1,1><<<dim3(512, 4, 1), 256, 0, stream>>>(sb, nullptr, 512, Wkb, Kt, 65536, 512, 512, 0, 0, 0, nullptr);
  gemm_bt<0,1><<<dim3(512, 4, 1), 256, 0, stream>>>(sb, nullptr, 512, Wvb, Vt, 65536, 512, 512, 0, 0, 0, nullptr);

  // 5. Ksum (contiguous rows of Kt)
  ksum_t<<<8192, 256, 0, stream>>>(Kt, Ksum);

  // 6. KVt[n][v,d] = sum_s Vt[v,s] * Kt[d,s]  — plain NT GEMM now
  gemm_bt<0,0><<<dim3(4, 4, 64), 256, 0, stream>>>(Vt, nullptr, 1024, Kt, KVt, 512, 512, 1024,
                                                   512L * 1024, 512L * 1024, 512L * 512, nullptr);

  // 7. Z
  z_kernel<<<16384, 256, 0, stream>>>(Qb, Ksum, Zbuf);

  // 8. msg[n,l,v] = (Q[n,l,:] . KVt[n][v,:]) * Z[n,l]
  gemm_bt<2,0><<<dim3(8, 4, 64), 256, 0, stream>>>(Qb, nullptr, 512, KVt, msg, 1024, 512, 512,
                                                   1024L * 512, 512L * 512, 1024L * 512, Zbuf);

  // 9. t1 = msg @ Wm^T
  gemm_bt<0,0><<<dim3(512, 4, 1), 256, 0, stream>>>(msg, nullptr, 512, Wmb, t1, 65536, 512, 512, 0, 0, 0, nullptr);

  // 10. msgn = LN(t1)*g1+b1
  ln_kernel<0><<<16384, 256, 0, stream>>>(t1, g1, b1, nullptr, msgn);

  // 11. h1 = relu([xb | msgn] @ W1^T)
  gemm_bt<3,0><<<dim3(512, 8, 1), 256, 0, stream>>>(xb, msgn, 512, W1b, h1, 65536, 1024, 1024, 0, 0, 0, nullptr);

  // 12. t2 = h1 @ W2^T
  gemm_bt<0,0><<<dim3(512, 4, 1), 256, 0, stream>>>(h1, nullptr, 1024, W2b, t2, 65536, 512, 1024, 0, 0, 0, nullptr);

  // 13. out = x + LN(t2)*g2+b2
  ln_kernel<1><<<16384, 256, 0, stream>>>(t2, g2, b2, x, out);

  (void)in_sizes; (void)n_in; (void)out_size; (void)ws_size;
}

// Round 3
// 1075.874 us; speedup vs baseline: 1.2678x; 1.0034x over previous
//
#include <hip/hip_runtime.h>

typedef __bf16 bf16;
typedef __bf16 bf16x4 __attribute__((ext_vector_type(4)));
typedef __bf16 bf16x8 __attribute__((ext_vector_type(8)));
typedef float f32x4 __attribute__((ext_vector_type(4)));

static_assert(sizeof(bf16x8) == 16, "bf16x8 must be 16B");

// async global->LDS, 16B per lane, lane-contiguous LDS destination
#define GLL16(gp, lp) __builtin_amdgcn_global_load_lds( \
    (__attribute__((address_space(1))) void*)(gp),      \
    (__attribute__((address_space(3))) void*)(lp), 16, 0, 0)

// ---------------- fp32 -> bf16 bulk convert ----------------
__global__ void cvt_f32_bf16(const float* __restrict__ src, bf16* __restrict__ dst, long n) {
  long i = ((long)blockIdx.x * 256 + threadIdx.x) * 8;
  long stride = (long)gridDim.x * 2048;
  for (; i < n; i += stride) {
    float4 a = *(const float4*)(src + i);
    float4 b = *(const float4*)(src + i + 4);
    bf16x8 o;
    o[0] = (bf16)a.x; o[1] = (bf16)a.y; o[2] = (bf16)a.z; o[3] = (bf16)a.w;
    o[4] = (bf16)b.x; o[5] = (bf16)b.y; o[6] = (bf16)b.z; o[7] = (bf16)b.w;
    *(bf16x8*)(dst + i) = o;
  }
}

// ---------------- generic NT GEMM: C[M,N] = A[M,K] * Bt[N,K]^T ----------------
// bn = blockIdx.x (FASTEST, few blocks) so all N-blocks of an M-tile run
// concurrently -> A tile fetched once into L2, small B stays hot.
// A may be a concat of two buffers along K (split at KA0, 64-aligned). Batched via blockIdx.z.
// EPI: 0 = none, 1 = elu(x)+1, 2 = * rowscale[row], 3 = relu.
// EPO: 0 = row-major bf16 C[M,N] (LDS-transpose, coalesced bf16x8 stores);
//      1 = per-batch transposed Ct[n][col, l], L=1024 rows/batch (projection use).
template<int EPI, int EPO>
__launch_bounds__(256)
__global__ void gemm_bt(const bf16* __restrict__ A0, const bf16* __restrict__ A1, int KA0,
                        const bf16* __restrict__ Bt, bf16* __restrict__ C,
                        int M, int N, int K,
                        long sAb, long sBb, long sCb,
                        const float* __restrict__ rowscale)
{
  constexpr int SMEM_BYTES = (128 * 132 * 2) > (2 * 128 * 64 * 2) ? (128 * 132 * 2) : (2 * 128 * 64 * 2);
  __shared__ __align__(16) char smem[SMEM_BYTES];
  bf16* sA = (bf16*)smem;          // [128][64], col-block XOR-swizzled by (row&7)
  bf16* sB = sA + 128 * 64;

  const int tid = threadIdx.x;
  const int lane = tid & 63, wave = tid >> 6;
  const int wm = (wave & 1) << 6, wn = (wave >> 1) << 6;
  const int lr = lane & 15, lq = lane >> 4;
  const long zb = blockIdx.z;
  const bf16* A0p = A0 + zb * sAb;
  const bf16* Btp = Bt + zb * sBb;
  bf16* Cp = C + zb * sCb;
  const int bm = blockIdx.y << 7, bn = blockIdx.x << 7;

  // staging geometry: wave w loads rows [w*32, w*32+32) of each tile, 4 insts x 8 rows
  const int srow = wave << 5;
  const int lrow = lane >> 3;                 // 0..7 within 8-row slab
  const int lcb  = (lane & 7) ^ lrow;         // swizzled col-block this lane fetches
  const int rbase = srow + lrow;

  // hoisted staging pointers, advanced +64 elems per K-iter
  const bf16* pA[4];
  const bf16* pB[4];
#pragma unroll
  for (int i = 0; i < 4; i++) {
    pA[i] = A0p + (long)(bm + rbase + (i << 3)) * KA0 + (lcb << 3);
    pB[i] = Btp + (long)(bn + rbase + (i << 3)) * K   + (lcb << 3);
  }

  f32x4 acc[4][4];
#pragma unroll
  for (int i = 0; i < 4; i++)
#pragma unroll
    for (int j = 0; j < 4; j++) acc[i][j] = (f32x4){0.f, 0.f, 0.f, 0.f};

  for (int k0 = 0; k0 < K; k0 += 64) {
    if (k0 == KA0) {           // switch to second A buffer (concat along K)
      const int KA1 = K - KA0;
#pragma unroll
      for (int i = 0; i < 4; i++)
        pA[i] = A1 + (long)(bm + rbase + (i << 3)) * KA1 + (lcb << 3);
    }
#pragma unroll
    for (int i = 0; i < 4; i++) {
      int r = srow + (i << 3);
      GLL16(pA[i], sA + (r << 6));
      GLL16(pB[i], sB + (r << 6));
      pA[i] += 64; pB[i] += 64;
    }
    __syncthreads();
#pragma unroll
    for (int kk = 0; kk < 64; kk += 32) {
      const int kbx = ((kk >> 3) + lq) ^ (lr & 7);  // swizzled block for this lane
      bf16x8 af[4], bfv[4];
#pragma unroll
      for (int t = 0; t < 4; t++) {
        af[t]  = *(const bf16x8*)(&sA[((wm + (t << 4) + lr) << 6) + (kbx << 3)]);
        bfv[t] = *(const bf16x8*)(&sB[((wn + (t << 4) + lr) << 6) + (kbx << 3)]);
      }
#pragma unroll
      for (int mt = 0; mt < 4; mt++)
#pragma unroll
        for (int nt = 0; nt < 4; nt++)
          acc[mt][nt] = __builtin_amdgcn_mfma_f32_16x16x32_bf16(af[mt], bfv[nt], acc[mt][nt], 0, 0, 0);
    }
    __syncthreads();
  }

  if constexpr (EPO == 0) {
    // transpose-free layout fix through LDS: acc (col=lane&15, row=lq*4+reg)
    // -> [128][132] row-major tile -> coalesced bf16x8 row stores.
    bf16* sT = (bf16*)smem;
#pragma unroll
    for (int mt = 0; mt < 4; mt++) {
#pragma unroll
      for (int r = 0; r < 4; r++) {
        int row = wm + (mt << 4) + (lq << 2) + r;
        float rs = 1.f;
        if constexpr (EPI == 2) rs = rowscale[zb * (long)M + bm + row];
#pragma unroll
        for (int nt = 0; nt < 4; nt++) {
          int col = wn + (nt << 4) + lr;
          float v = acc[mt][nt][r];
          if constexpr (EPI == 1) v = v > 0.f ? v + 1.f : __expf(v);
          if constexpr (EPI == 2) v = v * rs;
          if constexpr (EPI == 3) v = v > 0.f ? v : 0.f;
          sT[row * 132 + col] = (bf16)v;
        }
      }
    }
    __syncthreads();
    const int col = (tid & 15) << 3;
    const int r0 = tid >> 4;
#pragma unroll
    for (int j = 0; j < 8; j++) {
      int row = (j << 4) + r0;
      bf16x8 v = *(const bf16x8*)(&sT[row * 132 + col]);
      *(bf16x8*)(&Cp[(long)(bm + row) * N + bn + col]) = v;
    }
  } else {
    // transposed per-batch output (projections): Ct[n][col, l]
    bf16* sT = (bf16*)smem;   // [128 cols][132]
#pragma unroll
    for (int nt = 0; nt < 4; nt++) {
      int tc = wn + (nt << 4) + lr;
#pragma unroll
      for (int mt = 0; mt < 4; mt++) {
        bf16x4 p;
#pragma unroll
        for (int r = 0; r < 4; r++) {
          float v = acc[mt][nt][r];
          if constexpr (EPI == 1) v = v > 0.f ? v + 1.f : __expf(v);
          p[r] = (bf16)v;
        }
        *(bf16x4*)(&sT[tc * 132 + wm + (mt << 4) + (lq << 2)]) = p;
      }
    }
    __syncthreads();
    const long nidx = bm >> 10;          // batch (L=1024 rows per batch, bm 128-aligned)
    const int lbase = bm & 1023;
    const int c8 = tid >> 3, part = tid & 7;
#pragma unroll
    for (int cg = 0; cg < 4; cg++) {
      int col = (cg << 5) + c8;
#pragma unroll
      for (int j = 0; j < 2; j++) {
        int ro = (j << 6) + (part << 3);
        bf16x8 v = *(const bf16x8*)(&sT[col * 132 + ro]);
        *(bf16x8*)(&C[nidx * (512L * 1024L) + (long)(bn + col) * 1024L + lbase + ro]) = v;
      }
    }
  }
}

// ---------------- Ksum[n,d] = sum_s Kt[n][d,s] (contiguous rows) ----------------
__launch_bounds__(256)
__global__ void ksum_t(const bf16* __restrict__ Kt, float* __restrict__ Ksum) {
  const int wave = threadIdx.x >> 6, lane = threadIdx.x & 63;
  const long row = (long)blockIdx.x * 4 + wave;       // row = n*512 + d, 32768 rows
  const bf16* p = Kt + row * 1024 + lane * 16;
  bf16x8 a = *(const bf16x8*)p;
  bf16x8 b = *(const bf16x8*)(p + 8);
  float s = 0.f;
#pragma unroll
  for (int j = 0; j < 8; j++) s += (float)a[j] + (float)b[j];
#pragma unroll
  for (int off = 32; off > 0; off >>= 1) s += __shfl_xor(s, off);
  if (lane == 0) Ksum[row] = s;
}

// ---------------- Z[row] = 1/(dot(Q[row], Ksum[n]) + eps), wave per row ----------------
__launch_bounds__(256)
__global__ void z_kernel(const bf16* __restrict__ Qb, const float* __restrict__ Ksum, float* __restrict__ Z) {
  const int wave = threadIdx.x >> 6, lane = threadIdx.x & 63;
  const long row = (long)blockIdx.x * 4 + wave;
  const long n = row >> 10;
  bf16x8 qv = *(const bf16x8*)(Qb + row * 512 + lane * 8);
  const float* ks = Ksum + n * 512 + lane * 8;
  float4 k0 = *(const float4*)ks;
  float4 k1 = *(const float4*)(ks + 4);
  float dot = (float)qv[0] * k0.x + (float)qv[1] * k0.y + (float)qv[2] * k0.z + (float)qv[3] * k0.w
            + (float)qv[4] * k1.x + (float)qv[5] * k1.y + (float)qv[6] * k1.z + (float)qv[7] * k1.w;
#pragma unroll
  for (int off = 32; off > 0; off >>= 1) dot += __shfl_xor(dot, off);
  if (lane == 0) Z[row] = 1.f / (dot + 1e-6f);
}

// ---------------- LayerNorm, wave per row of 512. MODE 0: bf16 out = LN*g+b.
// MODE 1: float out = xres + LN*g+b ----------------
template<int MODE>
__launch_bounds__(256)
__global__ void ln_kernel(const bf16* __restrict__ T, const float* __restrict__ g, const float* __restrict__ b,
                          const float* __restrict__ xres, void* __restrict__ outp)
{
  const int wave = threadIdx.x >> 6, lane = threadIdx.x & 63;
  const long row = (long)blockIdx.x * 4 + wave;
  const int c = lane * 8;
  bf16x8 tv = *(const bf16x8*)(T + row * 512 + c);
  float v[8]; float s = 0.f;
#pragma unroll
  for (int j = 0; j < 8; j++) { v[j] = (float)tv[j]; s += v[j]; }
#pragma unroll
  for (int off = 32; off > 0; off >>= 1) s += __shfl_xor(s, off);
  const float mu = s * (1.f / 512.f);
  float q = 0.f;
#pragma unroll
  for (int j = 0; j < 8; j++) { float d = v[j] - mu; q += d * d; }
#pragma unroll
  for (int off = 32; off > 0; off >>= 1) q += __shfl_xor(q, off);
  const float rstd = rsqrtf(q * (1.f / 512.f) + 1e-5f);
  float h[8];
#pragma unroll
  for (int j = 0; j < 8; j++) h[j] = (v[j] - mu) * rstd * g[c + j] + b[c + j];
  if constexpr (MODE == 0) {
    bf16x8 o;
#pragma unroll
    for (int j = 0; j < 8; j++) o[j] = (bf16)h[j];
    *(bf16x8*)((bf16*)outp + row * 512 + c) = o;
  } else {
    const float* xr = xres + row * 512 + c;
    float4 x0 = *(const float4*)xr, x1 = *(const float4*)(xr + 4);
    float4 o0 = {x0.x + h[0], x0.y + h[1], x0.z + h[2], x0.w + h[3]};
    float4 o1 = {x1.x + h[4], x1.y + h[5], x1.z + h[6], x1.w + h[7]};
    float* op = (float*)outp + row * 512 + c;
    *(float4*)op = o0;
    *(float4*)(op + 4) = o1;
  }
}

// ---------------- launch ----------------
extern "C" void kernel_launch(void* const* d_in, const int* in_sizes, int n_in,
                              void* d_out, int out_size, void* d_ws, size_t ws_size,
                              hipStream_t stream) {
  const float* x      = (const float*)d_in[0];
  const float* source = (const float*)d_in[1];
  const float* Wq = (const float*)d_in[2];
  const float* Wk = (const float*)d_in[3];
  const float* Wv = (const float*)d_in[4];
  const float* Wm = (const float*)d_in[5];
  const float* W1 = (const float*)d_in[6];
  const float* W2 = (const float*)d_in[7];
  const float* g1 = (const float*)d_in[8];
  const float* b1 = (const float*)d_in[9];
  const float* g2 = (const float*)d_in[10];
  const float* b2 = (const float*)d_in[11];
  float* out = (float*)d_out;

  char* ws = (char*)d_ws;
  bf16* xb   = (bf16*)(ws + 0L);           // 64 MB
  bf16* sb   = (bf16*)(ws + 67108864L);    // 64 MB -> reused as msgn
  bf16* Qb   = (bf16*)(ws + 134217728L);   // 64 MB -> reused (with Kt slot) as h1
  bf16* Kt   = (bf16*)(ws + 201326592L);   // 64 MB [n][d][s] -> reused as WKV
  bf16* Vt   = (bf16*)(ws + 268435456L);   // 64 MB [n][v][s] -> reused as t1/t2
  bf16* KV   = (bf16*)(ws + 335544320L);   // 32 MB [n][d][v]
  float* Ksum = (float*)(ws + 369098752L); // 128 KB
  float* Zbuf = (float*)(ws + 369229824L); // 256 KB
  bf16* Wqb = (bf16*)(ws + 369491968L);
  bf16* Wkb = (bf16*)(ws + 370016256L);
  bf16* Wvb = (bf16*)(ws + 370540544L);
  bf16* Wmb = (bf16*)(ws + 371064832L);
  bf16* W1b = (bf16*)(ws + 371589120L);
  bf16* W2b = (bf16*)(ws + 373686272L);
  bf16* WKV  = Kt;   // [n][i][d] 32 MB, Kt dead after KV+Ksum
  bf16* t1   = Vt;   // Vt dead after KV
  bf16* msgn = sb;
  bf16* h1   = Qb;   // 128 MB spanning Qb+Kt slots
  bf16* t2   = Vt;

  // 1. fp32 -> bf16
  cvt_f32_bf16<<<16384, 256, 0, stream>>>(x, xb, 33554432L);
  cvt_f32_bf16<<<16384, 256, 0, stream>>>(source, sb, 33554432L);
  cvt_f32_bf16<<<128, 256, 0, stream>>>(Wq, Wqb, 262144L);
  cvt_f32_bf16<<<128, 256, 0, stream>>>(Wk, Wkb, 262144L);
  cvt_f32_bf16<<<128, 256, 0, stream>>>(Wv, Wvb, 262144L);
  cvt_f32_bf16<<<128, 256, 0, stream>>>(Wm, Wmb, 262144L);
  cvt_f32_bf16<<<512, 256, 0, stream>>>(W1, W1b, 1048576L);
  cvt_f32_bf16<<<256, 256, 0, stream>>>(W2, W2b, 524288L);

  // 2-4. projections. Q normal layout; K,V transposed per batch (EPO=1).
  gemm_bt<1,0><<<dim3(4, 512, 1), 256, 0, stream>>>(xb, nullptr, 512, Wqb, Qb, 65536, 512, 512, 0, 0, 0, nullptr);
  gemm_bt<1,1><<<dim3(4, 512, 1), 256, 0, stream>>>(sb, nullptr, 512, Wkb, Kt, 65536, 512, 512, 0, 0, 0, nullptr);
  gemm_bt<0,1><<<dim3(4, 512, 1), 256, 0, stream>>>(sb, nullptr, 512, Wvb, Vt, 65536, 512, 512, 0, 0, 0, nullptr);

  // 5. Ksum (contiguous rows of Kt)
  ksum_t<<<8192, 256, 0, stream>>>(Kt, Ksum);

  // 6. KV[n][d,v] = sum_s Kt[d,s] * Vt[v,s]
  gemm_bt<0,0><<<dim3(4, 4, 64), 256, 0, stream>>>(Kt, nullptr, 1024, Vt, KV, 512, 512, 1024,
                                                   512L * 1024, 512L * 1024, 512L * 512, nullptr);

  // 6b. WKV[n][i,d] = sum_v Wm[i,v] * KV[n][d,v]   (Wm folded in here)
  gemm_bt<0,0><<<dim3(4, 4, 64), 256, 0, stream>>>(Wmb, nullptr, 512, KV, WKV, 512, 512, 512,
                                                   0, 512L * 512, 512L * 512, nullptr);

  // 7. Z
  z_kernel<<<16384, 256, 0, stream>>>(Qb, Ksum, Zbuf);

  // 8. t1[n][l,i] = Z[n,l] * sum_d Q[n][l,d] * WKV[n][i,d]
  gemm_bt<2,0><<<dim3(4, 8, 64), 256, 0, stream>>>(Qb, nullptr, 512, WKV, t1, 1024, 512, 512,
                                                   1024L * 512, 512L * 512, 1024L * 512, Zbuf);

  // 10. msgn = LN(t1)*g1+b1
  ln_kernel<0><<<16384, 256, 0, stream>>>(t1, g1, b1, nullptr, msgn);

  // 11. h1 = relu([xb | msgn] @ W1^T)
  gemm_bt<3,0><<<dim3(8, 512, 1), 256, 0, stream>>>(xb, msgn, 512, W1b, h1, 65536, 1024, 1024, 0, 0, 0, nullptr);

  // 12. t2 = h1 @ W2^T
  gemm_bt<0,0><<<dim3(4, 512, 1), 256, 0, stream>>>(h1, nullptr, 1024, W2b, t2, 65536, 512, 1024, 0, 0, 0, nullptr);

  // 13. out = x + LN(t2)*g2+b2
  ln_kernel<1><<<16384, 256, 0, stream>>>(t2, g2, b2, x, out);

  (void)in_sizes; (void)n_in; (void)out_size; (void)ws_size;
}